// Round 1
// baseline (116.870 us; speedup 1.0000x reference)
//
#include <hip/hip_runtime.h>
#include <math.h>

// Problem constants (DigitCapsules)
#define B_   64
#define IC   32
#define D_   288   // ICH*WID*HEI = 8*6*6
#define OC   10
#define OCH  16
#define J_   160   // OC*OCH
#define BJ   10240 // B_*J_

// K1: u_sum[ic][b*160+j] = sum_d u[b,ic,d] * W[ic,d,j];  u_dot[ic,o] = sum_{b,e} u_sum
// grid: 256 blocks = ic(32) x btile(8); block 256 = b_sub(8) x j_lane(32), 5 j's per thread
__global__ __launch_bounds__(256) void k_usum(const float* __restrict__ u,
                                              const float* __restrict__ Wt,
                                              float* __restrict__ US,
                                              float* __restrict__ UD) {
    const int ic  = blockIdx.x & 31;
    const int bt  = blockIdx.x >> 5;
    const int tid = threadIdx.x;
    __shared__ float u_lds[8 * D_];
    __shared__ float ud_part[OC];
    if (tid < OC) ud_part[tid] = 0.f;
    for (int idx = tid; idx < 8 * D_; idx += 256) {
        int b_sub = idx / D_;
        int d     = idx - b_sub * D_;
        int b     = bt * 8 + b_sub;
        u_lds[idx] = u[(b * IC + ic) * D_ + d];
    }
    __syncthreads();
    const int b_sub = tid >> 5;   // 0..7
    const int jl    = tid & 31;   // 0..31
    const float* wbase = Wt + (size_t)ic * D_ * J_ + jl;
    const float* ur    = &u_lds[b_sub * D_];
    float a0 = 0.f, a1 = 0.f, a2 = 0.f, a3 = 0.f, a4 = 0.f;
    #pragma unroll 4
    for (int d = 0; d < D_; ++d) {
        float uv = ur[d];
        const float* wr = wbase + d * J_;
        a0 += uv * wr[0];
        a1 += uv * wr[32];
        a2 += uv * wr[64];
        a3 += uv * wr[96];
        a4 += uv * wr[128];
    }
    const int b = bt * 8 + b_sub;
    float* usp = US + (size_t)ic * BJ + b * J_ + jl;
    usp[0]   = a0;
    usp[32]  = a1;
    usp[64]  = a2;
    usp[96]  = a3;
    usp[128] = a4;
    // partial u_dot over this block's 8 b's, grouped by o = j/16
    atomicAdd(&ud_part[(jl       ) >> 4], a0);
    atomicAdd(&ud_part[(jl + 32  ) >> 4], a1);
    atomicAdd(&ud_part[(jl + 64  ) >> 4], a2);
    atomicAdd(&ud_part[(jl + 96  ) >> 4], a3);
    atomicAdd(&ud_part[(jl + 128 ) >> 4], a4);
    __syncthreads();
    if (tid < OC) atomicAdd(&UD[ic * OC + tid], ud_part[tid]);
}

// K2 (run for k=0,1,2): replay logit chain from n[0..k-1], compute c^k, then
// s[t] = sum_i c[i,o]*US[i][t]; accumulate n_k = sum|s|; store s.
// grid: 40 blocks x 256 threads = 10240 = one thread per (b,o,e)
__global__ __launch_bounds__(256) void k_route(const float* __restrict__ US,
                                               const float* __restrict__ UD,
                                               float* __restrict__ nacc,
                                               float* __restrict__ s_buf,
                                               int k) {
    __shared__ float bij[IC * OC];
    __shared__ float cij[IC * OC];
    __shared__ float ud[IC * OC];
    __shared__ float wred[4];
    const int tid = threadIdx.x;
    for (int i = tid; i < IC * OC; i += 256) {
        ud[i]  = UD[i];
        bij[i] = 0.f;
    }
    __syncthreads();
    if (tid < OC) {
        const int o = tid;
        for (int q = 0; q <= k; ++q) {
            // softmax over i (axis 0) for column o
            float mx = -1e30f;
            for (int i = 0; i < IC; ++i) mx = fmaxf(mx, bij[i * OC + o]);
            float se = 0.f;
            for (int i = 0; i < IC; ++i) {
                float e = expf(bij[i * OC + o] - mx);
                cij[i * OC + o] = e;
                se += e;
            }
            float inv = 1.f / se;
            float ss = 0.f;
            for (int i = 0; i < IC; ++i) {
                float c = cij[i * OC + o] * inv;
                cij[i * OC + o] = c;
                ss += c * ud[i * OC + o];
            }
            if (q < k) {
                float n  = nacc[q];
                float n2 = n * n;
                float w  = (n2 / (1.f + n2)) * (ss / n);  // coef * sum(v)/... rank-1 update
                for (int i = 0; i < IC; ++i) bij[i * OC + o] += ud[i * OC + o] * w;
            }
        }
    }
    __syncthreads();
    const int t = blockIdx.x * 256 + tid;     // 0..10239 = b*160 + o*16 + e
    const int o = (t >> 4) % OC;
    float s = 0.f;
    const float* usp = US + t;
    #pragma unroll
    for (int i = 0; i < IC; ++i) s += cij[i * OC + o] * usp[(size_t)i * BJ];
    s_buf[t] = s;
    float a = fabsf(s);
    #pragma unroll
    for (int off = 32; off > 0; off >>= 1) a += __shfl_down(a, off);
    if ((tid & 63) == 0) wred[tid >> 6] = a;
    __syncthreads();
    if (tid == 0) atomicAdd(&nacc[k], wred[0] + wred[1] + wred[2] + wred[3]);
}

// K3: v = (n^2/(1+n^2)) * (s/n), matching the reference's operation order
__global__ __launch_bounds__(256) void k_final(const float* __restrict__ s_buf,
                                               const float* __restrict__ nacc,
                                               float* __restrict__ out) {
    const int t = blockIdx.x * 256 + threadIdx.x;
    const float n    = nacc[2];
    const float coef = (n * n) / (1.f + n * n);
    out[t] = coef * (s_buf[t] / n);
}

extern "C" void kernel_launch(void* const* d_in, const int* in_sizes, int n_in,
                              void* d_out, int out_size, void* d_ws, size_t ws_size,
                              hipStream_t stream) {
    (void)in_sizes; (void)n_in; (void)out_size; (void)ws_size;
    const float* u  = (const float*)d_in[0];
    const float* Wt = (const float*)d_in[1];
    float* ws    = (float*)d_ws;
    float* US    = ws;              // 327680 floats: [ic=32][b*160+j = 10240]
    float* s_buf = ws + 327680;     // 10240 floats
    float* UD    = ws + 337920;     // 320 floats [ic=32][oc=10]
    float* nacc  = ws + 338240;     // 3 floats: n_0, n_1, n_2

    // ws is poisoned to 0xAA before every launch — zero the accumulators
    hipMemsetAsync((void*)UD, 0, (IC * OC + 3) * sizeof(float), stream);

    k_usum<<<dim3(256), dim3(256), 0, stream>>>(u, Wt, US, UD);
    for (int k = 0; k < 3; ++k)
        k_route<<<dim3(40), dim3(256), 0, stream>>>(US, UD, nacc, s_buf, k);
    k_final<<<dim3(40), dim3(256), 0, stream>>>(s_buf, nacc, (float*)d_out);
}

// Round 2
// 101.472 us; speedup vs baseline: 1.1517x; 1.1517x over previous
//
#include <hip/hip_runtime.h>
#include <math.h>

// Problem constants (DigitCapsules)
#define B_   64
#define IC   32
#define D_   288   // ICH*WID*HEI = 8*6*6
#define OC   10
#define OCH  16
#define J_   160   // OC*OCH
#define BJ   10240 // B_*J_

// K1: u_sum[ic][b*160+j] = sum_d u[b,ic,d] * W[ic,d,j]
//     UDp[block][o] = partial u_dot (sum over this block's 2 b's, e within o)
// grid: 1024 blocks = ic(32) x bt(32, 2 b's each); block 320 = b_sub(2) x j(160)
// 1 output/thread -> 5120 waves = 20 waves/CU (vs 4 before): latency hiding via TLP.
__global__ __launch_bounds__(320) void k_usum(const float* __restrict__ u,
                                              const float* __restrict__ Wt,
                                              float* __restrict__ US,
                                              float* __restrict__ UDp) {
    const int ic  = blockIdx.x >> 5;   // consecutive blocks share ic -> L2 reuse of W stream
    const int bt  = blockIdx.x & 31;
    const int tid = threadIdx.x;
    __shared__ float u_lds[2 * D_];
    __shared__ float ud_part[OC];
    if (tid < OC) ud_part[tid] = 0.f;
    for (int idx = tid; idx < 2 * D_; idx += 320) {
        int b_sub = idx / D_;
        int d     = idx - b_sub * D_;
        int b     = bt * 2 + b_sub;
        u_lds[idx] = u[(b * IC + ic) * D_ + d];
    }
    __syncthreads();
    const int j     = tid % 160;       // lane-consecutive -> coalesced W loads
    const int b_sub = tid / 160;
    const float* wp = Wt + (size_t)ic * D_ * J_ + j;
    const float* ur = u_lds + b_sub * D_;
    float acc0 = 0.f, acc1 = 0.f;
    #pragma unroll 8
    for (int d = 0; d < D_; d += 2) {
        acc0 += ur[d]     * wp[d * J_];
        acc1 += ur[d + 1] * wp[(d + 1) * J_];
    }
    float acc = acc0 + acc1;
    const int b = bt * 2 + b_sub;
    US[(size_t)ic * BJ + b * J_ + j] = acc;
    // o-group (16 consecutive j's, 16-lane aligned) shuffle reduce, then LDS, plain store
    float g = acc;
    g += __shfl_xor(g, 8, 16);
    g += __shfl_xor(g, 4, 16);
    g += __shfl_xor(g, 2, 16);
    g += __shfl_xor(g, 1, 16);
    if ((tid & 15) == 0) atomicAdd(&ud_part[j >> 4], g);   // LDS atomic, 20 leaders
    __syncthreads();
    if (tid < OC) UDp[blockIdx.x * OC + tid] = ud_part[tid];
}

// K2 (k=0,1,2): reduce UDp -> ud[ic][o]; reduce nblk -> n_q history; replay logit
// chain; s[t] = sum_i c[i,o]*US[i][t]; block |s| partial -> nblk[k][block] (plain store).
// grid: 40 x 256 = one thread per (b,o,e)
__global__ __launch_bounds__(256) void k_route(const float* __restrict__ US,
                                               const float* __restrict__ UDp,
                                               float* __restrict__ nblk,
                                               float* __restrict__ s_buf,
                                               int k) {
    __shared__ float bij[IC * OC];
    __shared__ float cij[IC * OC];
    __shared__ float ud[IC * OC];
    __shared__ float nq[2];
    __shared__ float wred[4];
    const int tid = threadIdx.x;
    for (int p = tid; p < IC * OC; p += 256) {
        int ic = p / 10, o = p - ic * 10;
        const float* q = UDp + ic * 320 + o;   // UDp[(ic*32+bt)*10+o]
        float s = 0.f;
        #pragma unroll
        for (int bt = 0; bt < 32; ++bt) s += q[bt * 10];
        ud[p]  = s;
        bij[p] = 0.f;
    }
    if (tid < k) {                             // n_q for q < k (k<=2 -> threads 0..1)
        const float* nb = nblk + tid * 64;
        float s = 0.f;
        #pragma unroll
        for (int b = 0; b < 40; ++b) s += nb[b];
        nq[tid] = s;
    }
    __syncthreads();
    if (tid < OC) {
        const int o = tid;
        for (int q = 0; q <= k; ++q) {
            float mx = -1e30f;
            for (int i = 0; i < IC; ++i) mx = fmaxf(mx, bij[i * OC + o]);
            float se = 0.f;
            for (int i = 0; i < IC; ++i) {
                float e = __expf(bij[i * OC + o] - mx);
                cij[i * OC + o] = e;
                se += e;
            }
            float inv = 1.f / se;
            float ss = 0.f;
            for (int i = 0; i < IC; ++i) {
                float c = cij[i * OC + o] * inv;
                cij[i * OC + o] = c;
                ss += c * ud[i * OC + o];
            }
            if (q < k) {
                float n  = nq[q];
                float n2 = n * n;
                float w  = (n2 / (1.f + n2)) * (ss / n);   // rank-1 b_ij update
                for (int i = 0; i < IC; ++i) bij[i * OC + o] += ud[i * OC + o] * w;
            }
        }
    }
    __syncthreads();
    const int t = blockIdx.x * 256 + tid;      // b*160 + o*16 + e
    const int o = (t >> 4) % OC;
    float s = 0.f;
    const float* usp = US + t;
    #pragma unroll
    for (int i = 0; i < IC; ++i) s += cij[i * OC + o] * usp[(size_t)i * BJ];
    if (k == 2) s_buf[t] = s;
    float a = fabsf(s);
    #pragma unroll
    for (int off = 32; off > 0; off >>= 1) a += __shfl_down(a, off);
    if ((tid & 63) == 0) wred[tid >> 6] = a;
    __syncthreads();
    if (tid == 0) nblk[k * 64 + blockIdx.x] = wred[0] + wred[1] + wred[2] + wred[3];
}

// K3: n = sum(nblk[2]); v = (n^2/(1+n^2)) * (s/n)
__global__ __launch_bounds__(256) void k_final(const float* __restrict__ s_buf,
                                               const float* __restrict__ nblk,
                                               float* __restrict__ out) {
    const int t = blockIdx.x * 256 + threadIdx.x;
    float n = 0.f;
    #pragma unroll
    for (int b = 0; b < 40; ++b) n += nblk[128 + b];   // broadcast L2 hits
    const float coef = (n * n) / (1.f + n * n);
    out[t] = coef * (s_buf[t] / n);
}

extern "C" void kernel_launch(void* const* d_in, const int* in_sizes, int n_in,
                              void* d_out, int out_size, void* d_ws, size_t ws_size,
                              hipStream_t stream) {
    (void)in_sizes; (void)n_in; (void)out_size; (void)ws_size;
    const float* u  = (const float*)d_in[0];
    const float* Wt = (const float*)d_in[1];
    float* ws    = (float*)d_ws;
    float* US    = ws;              // 327680 floats: [ic=32][b*160+j]
    float* s_buf = ws + 327680;     // 10240 floats
    float* UDp   = ws + 337920;     // 10240 floats: [block=1024][o=10]
    float* nblk  = ws + 348160;     // 192 floats: [k=3][64]

    // No memset: all ws reads are of values written earlier in this same graph
    // (UDp plain stores from k_usum; nblk[k][0..39] stored by k_route(k)).
    k_usum<<<dim3(1024), dim3(320), 0, stream>>>(u, Wt, US, UDp);
    for (int k = 0; k < 3; ++k)
        k_route<<<dim3(40), dim3(256), 0, stream>>>(US, UDp, nblk, s_buf, k);
    k_final<<<dim3(40), dim3(256), 0, stream>>>(s_buf, nblk, (float*)d_out);
}

// Round 3
// 98.783 us; speedup vs baseline: 1.1831x; 1.0272x over previous
//
#include <hip/hip_runtime.h>
#include <math.h>

// Problem constants (DigitCapsules)
#define B_   64
#define IC   32
#define D_   288   // ICH*WID*HEI = 8*6*6
#define OC   10
#define OCH  16
#define J_   160   // OC*OCH
#define BJ   10240 // B_*J_

// K1: u_sum[ic][b*160+j] = sum_d u[b,ic,d] * W[ic,d,j]
//     UDp[block][o] = partial u_dot for this block's 4 b's
// grid: 512 blocks = ic(32) x bt(16, 4 b's each); block 320 = b_sub(4) x j2(80)
// float2 W loads: 512 B/wave-load, halves VMEM instruction count vs scalar.
// 512 blocks x 5 waves = 10 waves/CU for latency hiding.
__global__ __launch_bounds__(320) void k_usum(const float* __restrict__ u,
                                              const float* __restrict__ Wt,
                                              float* __restrict__ US,
                                              float* __restrict__ UDp) {
    const int ic  = blockIdx.x >> 4;
    const int bt  = blockIdx.x & 15;
    const int tid = threadIdx.x;
    __shared__ float u_lds[4 * D_];
    __shared__ float ud_part[OC];
    if (tid < OC) ud_part[tid] = 0.f;
    for (int idx = tid; idx < 4 * D_; idx += 320) {
        int b_sub = idx / D_;
        int d     = idx - b_sub * D_;
        int b     = bt * 4 + b_sub;
        u_lds[idx] = u[(b * IC + ic) * D_ + d];
    }
    __syncthreads();
    const int j2    = tid % 80;        // float2 index: j = 2*j2, 2*j2+1
    const int b_sub = tid / 80;
    const float2* wp = (const float2*)(Wt + (size_t)ic * D_ * J_) + j2;
    const float* ur  = u_lds + b_sub * D_;
    float ax = 0.f, ay = 0.f;
    #pragma unroll 16
    for (int d = 0; d < D_; ++d) {
        float2 w  = wp[d * 80];
        float  uv = ur[d];
        ax += uv * w.x;
        ay += uv * w.y;
    }
    const int b = bt * 4 + b_sub;
    ((float2*)(US + (size_t)ic * BJ + b * J_))[j2] = make_float2(ax, ay);
    // u_dot partial: both j's of a thread share o = j2>>3; o-group = 8 lanes, aligned
    float g = ax + ay;
    g += __shfl_xor(g, 1);
    g += __shfl_xor(g, 2);
    g += __shfl_xor(g, 4);
    if ((tid & 7) == 0) atomicAdd(&ud_part[j2 >> 3], g);  // LDS atomic, 40 leaders
    __syncthreads();
    if (tid < OC) UDp[blockIdx.x * OC + tid] = ud_part[tid];
}

// K2 (k=0,1,2): header replay fully parallel — one thread per (i,o), width-32
// shuffle softmax, b_ij in registers. k=0 reduces UDp once -> UD (global, reused
// k=1,2). s[t] = sum_i c[i,o]*US[i][t]; block |s| partial -> nblk[k][blk].
// grid: 32 x 320 = one thread per (b,o,e)
__global__ __launch_bounds__(320) void k_route(const float* __restrict__ US,
                                               const float* __restrict__ UDp,
                                               float* __restrict__ UD,
                                               float* __restrict__ nblk,
                                               float* __restrict__ s_buf,
                                               int k) {
    const int tid = threadIdx.x;
    const int i   = tid & 31;          // in-capsule, shuffle-width-32 minor
    const int o   = tid >> 5;          // 0..9
    __shared__ float cij[IC * OC];
    __shared__ float nqs[2];
    __shared__ float wred[5];
    float udv;
    if (k == 0) {
        float s = 0.f;
        #pragma unroll
        for (int bt = 0; bt < 16; ++bt) s += UDp[(i * 16 + bt) * OC + o];
        udv = s;
        UD[i * OC + o] = s;            // all blocks write identical values: benign
    } else {
        udv = UD[i * OC + o];
    }
    if (tid < k) {                     // n_q history, q < k (k<=2)
        const float* nb = nblk + tid * 64;
        float s = 0.f;
        #pragma unroll
        for (int b = 0; b < 32; ++b) s += nb[b];
        nqs[tid] = s;
    }
    __syncthreads();
    float bij = 0.f, c = 0.f;
    for (int q = 0; q <= k; ++q) {
        // softmax over i (32 lanes) for this o
        float m = bij;
        m = fmaxf(m, __shfl_xor(m, 16, 32));
        m = fmaxf(m, __shfl_xor(m,  8, 32));
        m = fmaxf(m, __shfl_xor(m,  4, 32));
        m = fmaxf(m, __shfl_xor(m,  2, 32));
        m = fmaxf(m, __shfl_xor(m,  1, 32));
        float e  = __expf(bij - m);
        float se = e;
        se += __shfl_xor(se, 16, 32);
        se += __shfl_xor(se,  8, 32);
        se += __shfl_xor(se,  4, 32);
        se += __shfl_xor(se,  2, 32);
        se += __shfl_xor(se,  1, 32);
        c = e / se;
        float cs = c * udv;            // Σ_i c·ud per o (butterfly: all lanes get it)
        cs += __shfl_xor(cs, 16, 32);
        cs += __shfl_xor(cs,  8, 32);
        cs += __shfl_xor(cs,  4, 32);
        cs += __shfl_xor(cs,  2, 32);
        cs += __shfl_xor(cs,  1, 32);
        if (q < k) {
            float n  = nqs[q];
            float n2 = n * n;
            bij += udv * ((n2 / (1.f + n2)) * (cs / n));   // rank-1 b_ij update
        }
    }
    cij[i * OC + o] = c;
    __syncthreads();
    const int t  = blockIdx.x * 320 + tid;   // b*160 + o*16 + e
    const int oo = (t >> 4) % OC;
    float s = 0.f;
    const float* usp = US + t;
    const float* cp  = cij + oo;
    #pragma unroll
    for (int ii = 0; ii < IC; ++ii) s += cp[ii * OC] * usp[(size_t)ii * BJ];
    if (k == 2) s_buf[t] = s;
    float a = fabsf(s);
    #pragma unroll
    for (int off = 32; off; off >>= 1) a += __shfl_down(a, off);
    if ((tid & 63) == 0) wred[tid >> 6] = a;
    __syncthreads();
    if (tid == 0)
        nblk[k * 64 + blockIdx.x] = wred[0] + wred[1] + wred[2] + wred[3] + wred[4];
}

// K3: n = sum(nblk[2]); v = (n^2/(1+n^2)) * (s/n)
__global__ __launch_bounds__(320) void k_final(const float* __restrict__ s_buf,
                                               const float* __restrict__ nblk,
                                               float* __restrict__ out) {
    const int t = blockIdx.x * 320 + threadIdx.x;
    float n = 0.f;
    #pragma unroll
    for (int b = 0; b < 32; ++b) n += nblk[128 + b];   // broadcast L2 hits
    const float coef = (n * n) / (1.f + n * n);
    out[t] = coef * (s_buf[t] / n);
}

extern "C" void kernel_launch(void* const* d_in, const int* in_sizes, int n_in,
                              void* d_out, int out_size, void* d_ws, size_t ws_size,
                              hipStream_t stream) {
    (void)in_sizes; (void)n_in; (void)out_size; (void)ws_size;
    const float* u  = (const float*)d_in[0];
    const float* Wt = (const float*)d_in[1];
    float* ws    = (float*)d_ws;
    float* US    = ws;              // 327680 floats: [ic=32][b*160+j]
    float* s_buf = ws + 327680;     // 10240 floats
    float* UDp   = ws + 337920;     // 5120 floats: [block=512][o=10]
    float* UD    = ws + 343040;     // 320 floats: [ic][o], written at k=0
    float* nblk  = ws + 343360;     // 192 floats: [k=3][64]

    // No memset: every ws location read was written earlier in this same graph.
    k_usum<<<dim3(512), dim3(320), 0, stream>>>(u, Wt, US, UDp);
    for (int k = 0; k < 3; ++k)
        k_route<<<dim3(32), dim3(320), 0, stream>>>(US, UDp, UD, nblk, s_buf, k);
    k_final<<<dim3(32), dim3(320), 0, stream>>>(s_buf, nblk, (float*)d_out);
}

// Round 4
// 85.572 us; speedup vs baseline: 1.3657x; 1.1544x over previous
//
#include <hip/hip_runtime.h>
#include <math.h>

// Problem constants (DigitCapsules)
#define B_   64
#define IC   32
#define D_   288   // ICH*WID*HEI = 8*6*6
#define OC   10
#define OCH  16
#define J_   160   // OC*OCH
#define BJ   10240 // B_*J_

// K1: u_sum[ic][b*160+j] = sum_d u[b,ic,d] * W[ic,d,j]
// grid 256 = ic(32) x bt(8); block 320 = b_sub(8) x j4(40); float4 W loads,
// explicit 8-deep load batches -> MLP=8 (round-1 version compiled to VGPR=20,
// i.e. ~2 outstanding loads -> pure latency stall at VALUBusy 3.8%).
// Also zero-inits the routing kernel's barrier/accumulators (block 0).
__global__ __launch_bounds__(320) void k_usum(const float* __restrict__ u,
                                              const float* __restrict__ Wt,
                                              float* __restrict__ US,
                                              float* __restrict__ UDp,
                                              float* __restrict__ nacc,
                                              int* __restrict__ bar) {
    const int ic  = blockIdx.x >> 3;
    const int bt  = blockIdx.x & 7;
    const int tid = threadIdx.x;
    __shared__ float u_lds[8 * D_];
    __shared__ float ud_part[OC];
    if (tid < OC) ud_part[tid] = 0.f;
    if (blockIdx.x == 0 && tid == 0) {
        nacc[0] = 0.f; nacc[1] = 0.f; nacc[2] = 0.f;
        *bar = 0;                       // k_route starts only after k_usum completes
    }
    for (int idx = tid; idx < 8 * D_; idx += 320) {
        int b_sub = idx / D_;
        int d     = idx - b_sub * D_;
        u_lds[idx] = u[((bt * 8 + b_sub) * IC + ic) * D_ + d];
    }
    __syncthreads();
    const int j4    = tid % 40;         // float4 index over j: lane-consecutive
    const int b_sub = tid / 40;
    const float4* wp = (const float4*)(Wt + (size_t)ic * D_ * J_) + j4;
    const float*  ur = u_lds + b_sub * D_;
    float ax = 0.f, ay = 0.f, az = 0.f, aw = 0.f;
    for (int d0 = 0; d0 < D_; d0 += 8) {
        float4 w0 = wp[(d0 + 0) * 40];
        float4 w1 = wp[(d0 + 1) * 40];
        float4 w2 = wp[(d0 + 2) * 40];
        float4 w3 = wp[(d0 + 3) * 40];
        float4 w4 = wp[(d0 + 4) * 40];
        float4 w5 = wp[(d0 + 5) * 40];
        float4 w6 = wp[(d0 + 6) * 40];
        float4 w7 = wp[(d0 + 7) * 40];
        float u0 = ur[d0 + 0], u1 = ur[d0 + 1], u2 = ur[d0 + 2], u3 = ur[d0 + 3];
        float u4 = ur[d0 + 4], u5 = ur[d0 + 5], u6 = ur[d0 + 6], u7 = ur[d0 + 7];
        ax += u0 * w0.x; ay += u0 * w0.y; az += u0 * w0.z; aw += u0 * w0.w;
        ax += u1 * w1.x; ay += u1 * w1.y; az += u1 * w1.z; aw += u1 * w1.w;
        ax += u2 * w2.x; ay += u2 * w2.y; az += u2 * w2.z; aw += u2 * w2.w;
        ax += u3 * w3.x; ay += u3 * w3.y; az += u3 * w3.z; aw += u3 * w3.w;
        ax += u4 * w4.x; ay += u4 * w4.y; az += u4 * w4.z; aw += u4 * w4.w;
        ax += u5 * w5.x; ay += u5 * w5.y; az += u5 * w5.z; aw += u5 * w5.w;
        ax += u6 * w6.x; ay += u6 * w6.y; az += u6 * w6.z; aw += u6 * w6.w;
        ax += u7 * w7.x; ay += u7 * w7.y; az += u7 * w7.z; aw += u7 * w7.w;
    }
    const int b = bt * 8 + b_sub;
    ((float4*)(US + (size_t)ic * BJ + b * J_))[j4] = make_float4(ax, ay, az, aw);
    // u_dot partial: 4 j's of one thread share o = j4>>2; 4-lane groups aligned (40%4==0)
    float g = ax + ay + az + aw;
    g += __shfl_xor(g, 1);
    g += __shfl_xor(g, 2);
    if ((tid & 3) == 0) atomicAdd(&ud_part[j4 >> 2], g);
    __syncthreads();
    if (tid < OC) UDp[blockIdx.x * OC + tid] = ud_part[tid];
}

// K2: ALL THREE routing iterations + final squash in one kernel.
// grid 32 x 320: one t=(b,o,e) per thread; s lives in a register across iters.
// Grid-wide sync among the 32 co-resident blocks via device-scope atomic
// barrier (monotone counter; zero-initialized by k_usum, which completes first).
__global__ __launch_bounds__(320) void k_route(const float* __restrict__ US,
                                               const float* __restrict__ UDp,
                                               float* __restrict__ nacc,
                                               int* __restrict__ bar,
                                               float* __restrict__ out) {
    const int tid = threadIdx.x;
    const int i   = tid & 31;          // in-capsule (shuffle width 32 minor)
    const int o   = tid >> 5;          // 0..9
    __shared__ float cij[OC * IC];     // [o][i]
    __shared__ float wred[5];
    __shared__ float nsh;
    // ud[i][o] = sum over k_usum's 8 b-tiles of UDp[(i*8+bt)*10+o]
    float udv = 0.f;
    #pragma unroll
    for (int bt = 0; bt < 8; ++bt) udv += UDp[(i * 8 + bt) * OC + o];
    const int t  = blockIdx.x * 320 + tid;   // b*160 + o*16 + e
    const int ot = (t >> 4) % OC;
    float bij = 0.f, s = 0.f;
    for (int q = 0; q < 3; ++q) {
        // softmax over i (32 lanes) for this o
        float m = bij;
        m = fmaxf(m, __shfl_xor(m, 16, 32));
        m = fmaxf(m, __shfl_xor(m,  8, 32));
        m = fmaxf(m, __shfl_xor(m,  4, 32));
        m = fmaxf(m, __shfl_xor(m,  2, 32));
        m = fmaxf(m, __shfl_xor(m,  1, 32));
        float e  = __expf(bij - m);
        float se = e;
        se += __shfl_xor(se, 16, 32);
        se += __shfl_xor(se,  8, 32);
        se += __shfl_xor(se,  4, 32);
        se += __shfl_xor(se,  2, 32);
        se += __shfl_xor(se,  1, 32);
        float c = e / se;
        cij[o * IC + i] = c;
        float cs = c * udv;            // Σ_i c·ud for this o (butterfly broadcast)
        cs += __shfl_xor(cs, 16, 32);
        cs += __shfl_xor(cs,  8, 32);
        cs += __shfl_xor(cs,  4, 32);
        cs += __shfl_xor(cs,  2, 32);
        cs += __shfl_xor(cs,  1, 32);
        __syncthreads();               // cij visible
        // s_t = Σ_i c[ot][i] * US[i][t] — 32 independent coalesced loads (MLP 32)
        float sv = 0.f;
        const float* usp = US + t;
        const float* cp  = cij + ot * IC;
        #pragma unroll
        for (int ii = 0; ii < IC; ++ii) sv += cp[ii] * usp[(size_t)ii * BJ];
        s = sv;
        // n_q = Σ|s| : wave butterfly -> block partial -> global atomic
        float a = fabsf(sv);
        #pragma unroll
        for (int off = 32; off; off >>= 1) a += __shfl_down(a, off);
        if ((tid & 63) == 0) wred[tid >> 6] = a;
        __syncthreads();
        if (tid == 0) {
            atomicAdd(nacc + q, wred[0] + wred[1] + wred[2] + wred[3] + wred[4]);
            __threadfence();
            atomicAdd(bar, 1);
            while (__hip_atomic_load(bar, __ATOMIC_ACQUIRE,
                                     __HIP_MEMORY_SCOPE_AGENT) < 32 * (q + 1))
                __builtin_amdgcn_s_sleep(1);
            nsh = __hip_atomic_load(nacc + q, __ATOMIC_RELAXED,
                                    __HIP_MEMORY_SCOPE_AGENT);
        }
        __syncthreads();
        const float n  = nsh;
        const float n2 = n * n;
        if (q < 2) {
            bij += udv * ((n2 / (1.f + n2)) * (cs / n));   // rank-1 b_ij update
        } else {
            out[t] = (n2 / (1.f + n2)) * (s / n);          // squash, final write
        }
    }
}

extern "C" void kernel_launch(void* const* d_in, const int* in_sizes, int n_in,
                              void* d_out, int out_size, void* d_ws, size_t ws_size,
                              hipStream_t stream) {
    (void)in_sizes; (void)n_in; (void)out_size; (void)ws_size;
    const float* u  = (const float*)d_in[0];
    const float* Wt = (const float*)d_in[1];
    float* ws   = (float*)d_ws;
    float* US   = ws;               // 327680 floats: [ic=32][b*160+j]
    float* UDp  = ws + 327680;      // 2560 floats: [block=256][o=10]
    float* nacc = ws + 330240;      // 3 floats
    int*   bar  = (int*)(ws + 330244);

    // 2 dispatches total. k_usum zero-inits nacc/bar (ws is poisoned 0xAA);
    // stream order guarantees they're ready before k_route starts.
    k_usum<<<dim3(256), dim3(320), 0, stream>>>(u, Wt, US, UDp, nacc, bar);
    k_route<<<dim3(32), dim3(320), 0, stream>>>(US, UDp, nacc, bar, (float*)d_out);
}

// Round 5
// 81.264 us; speedup vs baseline: 1.4382x; 1.0530x over previous
//
#include <hip/hip_runtime.h>
#include <math.h>

// Problem constants (DigitCapsules)
#define B_   64
#define IC   32
#define D_   288   // ICH*WID*HEI = 8*6*6
#define OC   10
#define OCH  16
#define J_   160   // OC*OCH
#define BJ   10240 // B_*J_

// K1: u_sum[ic][b*160+j] = sum_d u[b,ic,d] * W[ic,d,j]
// grid 512 = bt(16) x ic(32, MINOR -> XCD = blockIdx%8 = ic%8: all 16 blocks
// sharing an ic slice of W land on the SAME XCD; W fetched once per XCD-L2,
// 5.9 MB total instead of 47 MB). block 320 = dh(2) x b_sub(4) x j4(40):
// d-chain split in half across thread pairs -> 18 serial MLP-8 batches.
// 2 blocks/CU -> 10 waves/CU TLP. Also zero-inits k_route's barrier/accums.
__global__ __launch_bounds__(320) void k_usum(const float* __restrict__ u,
                                              const float* __restrict__ Wt,
                                              float* __restrict__ US,
                                              float* __restrict__ UDp,
                                              float* __restrict__ nacc,
                                              int* __restrict__ bar) {
    const int ic  = blockIdx.x & 31;
    const int bt  = blockIdx.x >> 5;    // 0..15
    const int tid = threadIdx.x;
    __shared__ float u_lds[4 * D_];     // [b_sub][d]
    __shared__ float part[640];         // dh=1 partials: [b_sub*40+j4] x float4
    __shared__ float ud_part[OC];
    if (tid < OC) ud_part[tid] = 0.f;
    if (blockIdx.x == 0 && tid == 0) {
        nacc[0] = 0.f; nacc[1] = 0.f; nacc[2] = 0.f;
        *bar = 0;                       // ready before k_route starts (stream order)
    }
    // stage u: 4 rows x 288 floats = 288 float4, coalesced
    for (int idx = tid; idx < 288; idx += 320) {
        int b_sub = idx / 72;
        int f4    = idx - b_sub * 72;
        int b     = bt * 4 + b_sub;
        ((float4*)u_lds)[idx] =
            ((const float4*)(u + (size_t)(b * IC + ic) * D_))[f4];
    }
    __syncthreads();
    const int j4    = tid % 40;         // float4 index over j (lane-consecutive)
    const int b_sub = (tid / 40) & 3;
    const int dh    = tid / 160;        // d-half: 0 or 1
    const float4* wp = (const float4*)(Wt + (size_t)ic * D_ * J_)
                       + (size_t)dh * 144 * 40 + j4;
    const float*  ur = u_lds + b_sub * D_ + dh * 144;
    float ax = 0.f, ay = 0.f, az = 0.f, aw = 0.f;
    for (int d0 = 0; d0 < 144; d0 += 8) {
        float4 w0 = wp[(d0 + 0) * 40];
        float4 w1 = wp[(d0 + 1) * 40];
        float4 w2 = wp[(d0 + 2) * 40];
        float4 w3 = wp[(d0 + 3) * 40];
        float4 w4 = wp[(d0 + 4) * 40];
        float4 w5 = wp[(d0 + 5) * 40];
        float4 w6 = wp[(d0 + 6) * 40];
        float4 w7 = wp[(d0 + 7) * 40];
        float u0 = ur[d0 + 0], u1 = ur[d0 + 1], u2 = ur[d0 + 2], u3 = ur[d0 + 3];
        float u4 = ur[d0 + 4], u5 = ur[d0 + 5], u6 = ur[d0 + 6], u7 = ur[d0 + 7];
        ax += u0 * w0.x; ay += u0 * w0.y; az += u0 * w0.z; aw += u0 * w0.w;
        ax += u1 * w1.x; ay += u1 * w1.y; az += u1 * w1.z; aw += u1 * w1.w;
        ax += u2 * w2.x; ay += u2 * w2.y; az += u2 * w2.z; aw += u2 * w2.w;
        ax += u3 * w3.x; ay += u3 * w3.y; az += u3 * w3.z; aw += u3 * w3.w;
        ax += u4 * w4.x; ay += u4 * w4.y; az += u4 * w4.z; aw += u4 * w4.w;
        ax += u5 * w5.x; ay += u5 * w5.y; az += u5 * w5.z; aw += u5 * w5.w;
        ax += u6 * w6.x; ay += u6 * w6.y; az += u6 * w6.z; aw += u6 * w6.w;
        ax += u7 * w7.x; ay += u7 * w7.y; az += u7 * w7.z; aw += u7 * w7.w;
    }
    if (dh == 1) ((float4*)part)[tid - 160] = make_float4(ax, ay, az, aw);
    __syncthreads();
    if (dh == 0) {
        float4 p = ((float4*)part)[tid];
        ax += p.x; ay += p.y; az += p.z; aw += p.w;
        ((float4*)(US + (size_t)ic * BJ + (bt * 4 + b_sub) * J_))[j4] =
            make_float4(ax, ay, az, aw);
        // u_dot partial: thread's 4 j's share o = j4>>2; aligned 4-lane groups
        float g = ax + ay + az + aw;
        g += __shfl_xor(g, 1);
        g += __shfl_xor(g, 2);
        if ((tid & 3) == 0) atomicAdd(&ud_part[j4 >> 2], g);
    }
    __syncthreads();
    if (tid < OC) UDp[blockIdx.x * OC + tid] = ud_part[tid];
}

// K2: all 3 routing iterations + squash, fused. grid 10 x 1024 = one t per
// thread; only 10 device-scope RMWs per barrier (vs 32 before). 16 waves/block
// hide the US-dot L3 latency. Blocks trivially co-resident (10 << 256 CUs).
__global__ __launch_bounds__(1024) void k_route(const float* __restrict__ US,
                                                const float* __restrict__ UDp,
                                                float* __restrict__ nacc,
                                                int* __restrict__ bar,
                                                float* __restrict__ out) {
    const int tid = threadIdx.x;
    const int i   = tid & 31;          // in-capsule (tid<320 path)
    const int o   = tid >> 5;          // 0..9     (tid<320 path)
    __shared__ float cij[OC * IC];     // [o][i]
    __shared__ float wred[16];
    __shared__ float nsh;
    float udv = 0.f;
    if (tid < 320) {                   // ud[i][o] = sum over 16 bt tiles
        #pragma unroll
        for (int bt = 0; bt < 16; ++bt) udv += UDp[(bt * 32 + i) * OC + o];
    }
    const int t  = blockIdx.x * 1024 + tid;   // b*160 + o*16 + e
    const int ot = (t >> 4) % OC;
    float bij = 0.f;
    for (int q = 0; q < 3; ++q) {
        float cs = 0.f;
        if (tid < 320) {
            // softmax over i (32 aligned lanes) for this o
            float m = bij;
            m = fmaxf(m, __shfl_xor(m, 16, 32));
            m = fmaxf(m, __shfl_xor(m,  8, 32));
            m = fmaxf(m, __shfl_xor(m,  4, 32));
            m = fmaxf(m, __shfl_xor(m,  2, 32));
            m = fmaxf(m, __shfl_xor(m,  1, 32));
            float e  = __expf(bij - m);
            float se = e;
            se += __shfl_xor(se, 16, 32);
            se += __shfl_xor(se,  8, 32);
            se += __shfl_xor(se,  4, 32);
            se += __shfl_xor(se,  2, 32);
            se += __shfl_xor(se,  1, 32);
            float c = e / se;
            cij[o * IC + i] = c;
            cs = c * udv;              // Σ_i c·ud for this o (butterfly)
            cs += __shfl_xor(cs, 16, 32);
            cs += __shfl_xor(cs,  8, 32);
            cs += __shfl_xor(cs,  4, 32);
            cs += __shfl_xor(cs,  2, 32);
            cs += __shfl_xor(cs,  1, 32);
        }
        __syncthreads();               // cij visible
        // s_t = Σ_i c[ot][i] * US[i][t] — 32 coalesced loads, MLP 32
        float s = 0.f;
        {
            const float* usp = US + t;
            const float* cp  = cij + ot * IC;
            #pragma unroll
            for (int ii = 0; ii < IC; ++ii) s += cp[ii] * usp[(size_t)ii * BJ];
        }
        float a = fabsf(s);
        #pragma unroll
        for (int off = 32; off; off >>= 1) a += __shfl_down(a, off);
        if ((tid & 63) == 0) wred[tid >> 6] = a;
        __syncthreads();
        if (tid == 0) {
            float blk = 0.f;
            #pragma unroll
            for (int w = 0; w < 16; ++w) blk += wred[w];
            atomicAdd(nacc + q, blk);
            __threadfence();
            atomicAdd(bar, 1);
            while (__hip_atomic_load(bar, __ATOMIC_ACQUIRE,
                                     __HIP_MEMORY_SCOPE_AGENT) < 10 * (q + 1))
                __builtin_amdgcn_s_sleep(1);
            nsh = __hip_atomic_load(nacc + q, __ATOMIC_RELAXED,
                                    __HIP_MEMORY_SCOPE_AGENT);
        }
        __syncthreads();
        const float n  = nsh;
        const float n2 = n * n;
        if (q < 2) {
            if (tid < 320) bij += udv * ((n2 / (1.f + n2)) * (cs / n));
        } else {
            out[t] = (n2 / (1.f + n2)) * (s / n);
        }
    }
}

extern "C" void kernel_launch(void* const* d_in, const int* in_sizes, int n_in,
                              void* d_out, int out_size, void* d_ws, size_t ws_size,
                              hipStream_t stream) {
    (void)in_sizes; (void)n_in; (void)out_size; (void)ws_size;
    const float* u  = (const float*)d_in[0];
    const float* Wt = (const float*)d_in[1];
    float* ws   = (float*)d_ws;
    float* US   = ws;               // 327680 floats: [ic=32][b*160+j]
    float* UDp  = ws + 327680;      // 5120 floats: [block=512][o=10]
    float* nacc = ws + 332800;      // 3 floats
    int*   bar  = (int*)(ws + 332803);

    // 2 dispatches. k_usum zero-inits nacc/bar (ws poisoned 0xAA each launch);
    // stream order guarantees readiness before k_route.
    k_usum<<<dim3(512), dim3(320), 0, stream>>>(u, Wt, US, UDp, nacc, bar);
    k_route<<<dim3(10), dim3(1024), 0, stream>>>(US, UDp, nacc, bar, (float*)d_out);
}